// Round 1
// baseline (437.667 us; speedup 1.0000x reference)
//
#include <hip/hip_runtime.h>
#include <hip/hip_bf16.h>
#include <math.h>

#define S_ 4
#define C_ 384
#define H_ 96
#define W_ 96
#define B_ 8
#define M_ 64
#define HW_ (H_ * W_)
#define EPSV 1e-6f
#define BETA_V 0.3f
#define TEMP_V 0.07f

__device__ __forceinline__ float block_sum(float v) {
    __shared__ float sm[8];
    int lane = threadIdx.x & 63;
    int wid = threadIdx.x >> 6;
#pragma unroll
    for (int o = 32; o; o >>= 1) v += __shfl_down(v, o, 64);
    if (lane == 0) sm[wid] = v;
    __syncthreads();
    int nw = blockDim.x >> 6;
    float r = 0.0f;
    for (int i = 0; i < nw; ++i) r += sm[i];
    __syncthreads();
    return r;
}

// One block per (s,c) plane: partial[s*C+c] = sum_p feats[s,c,p] * mask[s,p]
__global__ __launch_bounds__(256) void k_gpartial(const float* __restrict__ feats,
                                                  const int* __restrict__ mask,
                                                  float* __restrict__ partial) {
    int sc = blockIdx.x;
    int s = sc / C_;
    const float* fp = feats + (size_t)sc * HW_;
    const int* mp = mask + (size_t)s * HW_;
    float acc = 0.0f;
    for (int i = threadIdx.x; i < HW_; i += blockDim.x)
        acc += fp[i] * (float)mp[i];
    float tot = block_sum(acc);
    if (threadIdx.x == 0) partial[sc] = tot;
}

// One block per anchor: window sums -> proto[m, :], msum[m]
__global__ __launch_bounds__(256) void k_local(const float* __restrict__ feats,
                                               const int* __restrict__ mask,
                                               const int* __restrict__ pos,
                                               const int* __restrict__ samp,
                                               const int* __restrict__ rad,
                                               float* __restrict__ proto,
                                               float* __restrict__ msum_out) {
    int m = blockIdx.x;
    int y = pos[2 * m + 0];
    int x = pos[2 * m + 1];
    int s = samp[m];
    int ri = rad[m];
    int r = (ri == 0) ? 4 : (ri == 1) ? 8 : 16;
    int y0 = max(y - r, 0), y1 = min(y + r + 1, H_);
    int x0 = max(x - r, 0), x1 = min(x + r + 1, W_);
    int ww = x1 - x0;
    int n = (y1 - y0) * ww;

    __shared__ float mwin[33 * 33];
    const int* mp = mask + (size_t)s * HW_;
    float macc = 0.0f;
    for (int i = threadIdx.x; i < n; i += blockDim.x) {
        int yy = y0 + i / ww;
        int xx = x0 + i % ww;
        float mv = (float)mp[yy * W_ + xx];
        mwin[i] = mv;
        macc += mv;
    }
    float msum = block_sum(macc);  // also makes mwin visible (contains barrier)
    if (threadIdx.x == 0) msum_out[m] = msum;
    float inv = 1.0f / (msum + EPSV);

    for (int c = threadIdx.x; c < C_; c += blockDim.x) {
        const float* fp = feats + ((size_t)s * C_ + c) * HW_;
        float acc = 0.0f;
        int i = 0;
        for (int yy = y0; yy < y1; ++yy) {
            const float* row = fp + yy * W_;
            for (int xx = x0; xx < x1; ++xx, ++i)
                acc += row[xx] * mwin[i];
        }
        proto[m * C_ + c] = acc * inv;
    }
}

// Single block: combine everything into the final C-vector v.
__global__ __launch_bounds__(256) void k_finalize(const int* __restrict__ mask,
                                                  const float* __restrict__ partial,
                                                  const float* __restrict__ msum,
                                                  const float* __restrict__ proto,
                                                  float* __restrict__ v) {
    // fg = sum of mask
    float acc = 0.0f;
    for (int i = threadIdx.x; i < S_ * HW_; i += blockDim.x)
        acc += (float)mask[i];
    float fg = block_sum(acc);
    float invfg = 1.0f / (fg + EPSV);

    __shared__ float gv[C_];
    for (int c = threadIdx.x; c < C_; c += blockDim.x) {
        float t = 0.0f;
        for (int s = 0; s < S_; ++s) t += partial[s * C_ + c];
        gv[c] = t * invfg;
    }
    __syncthreads();

    float sq = 0.0f;
    for (int c = threadIdx.x; c < C_; c += blockDim.x) sq += gv[c] * gv[c];
    float gn = block_sum(sq);
    gn = fmaxf(sqrtf(gn), 1e-12f);

    // T = sum msum; weights[m] = msum[m]/(T+EPS); wsum = sum weights; w = weights/(wsum+EPS)
    float wa = 0.0f;
    for (int m = threadIdx.x; m < M_; m += blockDim.x) wa += msum[m];
    float T = block_sum(wa);
    float wb = 0.0f;
    for (int m = threadIdx.x; m < M_; m += blockDim.x) wb += msum[m] / (T + EPSV);
    float wsum = block_sum(wb);

    __shared__ float pn[M_];
    for (int m = 0; m < M_; ++m) {
        float a = 0.0f;
        for (int c = threadIdx.x; c < C_; c += blockDim.x) {
            float p = proto[m * C_ + c];
            a += p * p;
        }
        float nr = block_sum(a);
        if (threadIdx.x == 0) pn[m] = fmaxf(sqrtf(nr), 1e-12f);
    }
    __syncthreads();

    for (int c = threadIdx.x; c < C_; c += blockDim.x) {
        float vl = 0.0f;
        for (int m = 0; m < M_; ++m) {
            float w = (msum[m] / (T + EPSV)) / (wsum + EPSV);
            vl += w * proto[m * C_ + c] / pn[m];
        }
        v[c] = BETA_V * (gv[c] / gn) + (1.0f - BETA_V) * vl;
    }
}

// One thread per query pixel: s = <q, v> / ||q||; write both logit planes.
__global__ __launch_bounds__(256) void k_score(const float* __restrict__ q,
                                               const float* __restrict__ v,
                                               float* __restrict__ out) {
    __shared__ float vs[C_];
    for (int c = threadIdx.x; c < C_; c += blockDim.x) vs[c] = v[c];
    __syncthreads();

    int tid = blockIdx.x * blockDim.x + threadIdx.x;
    int b = tid / HW_;
    int p = tid - b * HW_;
    const float* qp = q + (size_t)b * C_ * HW_ + p;

    float dot = 0.0f, sq = 0.0f;
#pragma unroll 8
    for (int c = 0; c < C_; ++c) {
        float val = qp[(size_t)c * HW_];
        dot += val * vs[c];
        sq += val * val;
    }
    float s = dot / fmaxf(sqrtf(sq), 1e-12f);
    float o = s / TEMP_V;
    float* ob = out + (size_t)b * 2 * HW_;
    ob[p] = -o;
    ob[HW_ + p] = o;
}

extern "C" void kernel_launch(void* const* d_in, const int* in_sizes, int n_in,
                              void* d_out, int out_size, void* d_ws, size_t ws_size,
                              hipStream_t stream) {
    const float* support_feats = (const float*)d_in[0];
    const int* support_masks = (const int*)d_in[1];
    const float* query_feats = (const float*)d_in[2];
    const int* anchor_pos = (const int*)d_in[3];
    const int* anchor_sample = (const int*)d_in[4];
    const int* anchor_radius = (const int*)d_in[5];
    float* out = (float*)d_out;

    float* ws = (float*)d_ws;
    float* ws_partial = ws;                 // S*C = 1536
    float* ws_msum = ws_partial + S_ * C_;  // 64
    float* ws_proto = ws_msum + M_;         // M*C = 24576
    float* ws_v = ws_proto + M_ * C_;       // 384

    k_gpartial<<<S_ * C_, 256, 0, stream>>>(support_feats, support_masks, ws_partial);
    k_local<<<M_, 256, 0, stream>>>(support_feats, support_masks, anchor_pos,
                                    anchor_sample, anchor_radius, ws_proto, ws_msum);
    k_finalize<<<1, 256, 0, stream>>>(support_masks, ws_partial, ws_msum, ws_proto, ws_v);
    k_score<<<(B_ * HW_) / 256, 256, 0, stream>>>(query_feats, ws_v, out);
}

// Round 2
// 98.430 us; speedup vs baseline: 4.4465x; 4.4465x over previous
//
#include <hip/hip_runtime.h>
#include <hip/hip_bf16.h>
#include <math.h>

#define S_ 4
#define C_ 384
#define H_ 96
#define W_ 96
#define B_ 8
#define M_ 64
#define HW_ (H_ * W_)
#define EPSV 1e-6f
#define BETA_V 0.3f
#define TEMP_V 0.07f

__device__ __forceinline__ float wave_sum(float v) {
#pragma unroll
    for (int o = 32; o; o >>= 1) v += __shfl_down(v, o, 64);
    return v;
}

__device__ __forceinline__ float block_sum(float v) {
    __shared__ float sm[8];
    int lane = threadIdx.x & 63;
    int wid = threadIdx.x >> 6;
    v = wave_sum(v);
    if (lane == 0) sm[wid] = v;
    __syncthreads();
    int nw = blockDim.x >> 6;
    float r = 0.0f;
    for (int i = 0; i < nw; ++i) r += sm[i];
    __syncthreads();
    return r;
}

// One block per (s,c) plane: partial[s*C+c] = sum_p feats[s,c,p] * mask[s,p]
// Vectorized float4/int4 (HW_ = 9216 divisible by 4).
__global__ __launch_bounds__(256) void k_gpartial(const float* __restrict__ feats,
                                                  const int* __restrict__ mask,
                                                  float* __restrict__ partial) {
    int sc = blockIdx.x;
    int s = sc / C_;
    const float4* fp = (const float4*)(feats + (size_t)sc * HW_);
    const int4* mp = (const int4*)(mask + (size_t)s * HW_);
    float acc = 0.0f;
    for (int i = threadIdx.x; i < HW_ / 4; i += blockDim.x) {
        float4 f = fp[i];
        int4 m = mp[i];
        acc += f.x * (float)m.x + f.y * (float)m.y + f.z * (float)m.z + f.w * (float)m.w;
    }
    float tot = block_sum(acc);
    if (threadIdx.x == 0) partial[sc] = tot;
}

// One block per (anchor m, channel-group of 4). 4 waves; wave w handles channel
// cg*4+w via lane-parallel window sum + shuffle reduce. Mask window staged in LDS.
__global__ __launch_bounds__(256) void k_local(const float* __restrict__ feats,
                                               const int* __restrict__ mask,
                                               const int* __restrict__ pos,
                                               const int* __restrict__ samp,
                                               const int* __restrict__ rad,
                                               float* __restrict__ proto,
                                               float* __restrict__ msum_out) {
    const int CG = C_ / 4;  // 96
    int m = blockIdx.x / CG;
    int cg = blockIdx.x % CG;
    int y = pos[2 * m + 0];
    int x = pos[2 * m + 1];
    int s = samp[m];
    int ri = rad[m];
    int r = (ri == 0) ? 4 : (ri == 1) ? 8 : 16;
    int y0 = max(y - r, 0), y1 = min(y + r + 1, H_);
    int x0 = max(x - r, 0), x1 = min(x + r + 1, W_);
    int ww = x1 - x0;
    int n = (y1 - y0) * ww;

    __shared__ float mwin[33 * 33];
    const int* mp = mask + (size_t)s * HW_;
    float macc = 0.0f;
    for (int i = threadIdx.x; i < n; i += blockDim.x) {
        int yy = y0 + i / ww;
        int xx = x0 + i % ww;
        float mv = (float)mp[yy * W_ + xx];
        mwin[i] = mv;
        macc += mv;
    }
    float msum = block_sum(macc);  // barrier inside also publishes mwin
    if (cg == 0 && threadIdx.x == 0) msum_out[m] = msum;
    float inv = 1.0f / (msum + EPSV);

    int wid = threadIdx.x >> 6;
    int lane = threadIdx.x & 63;
    int c = cg * 4 + wid;
    const float* fp = feats + ((size_t)s * C_ + c) * HW_;
    float acc = 0.0f;
    for (int i = lane; i < n; i += 64) {
        int yy = y0 + i / ww;
        int xx = x0 + i % ww;
        acc += fp[yy * W_ + xx] * mwin[i];
    }
    acc = wave_sum(acc);
    if (lane == 0) proto[m * C_ + c] = acc * inv;
}

// Single block: combine everything into the final C-vector v.
__global__ __launch_bounds__(256) void k_finalize(const int* __restrict__ mask,
                                                  const float* __restrict__ partial,
                                                  const float* __restrict__ msum,
                                                  const float* __restrict__ proto,
                                                  float* __restrict__ v) {
    int tid = threadIdx.x;
    int wid = tid >> 6;
    int lane = tid & 63;

    // fg = sum of mask (int4 vectorized; S_*HW_ = 36864 divisible by 4)
    const int4* mp4 = (const int4*)mask;
    float acc = 0.0f;
    for (int i = tid; i < S_ * HW_ / 4; i += blockDim.x) {
        int4 m = mp4[i];
        acc += (float)(m.x + m.y + m.z + m.w);
    }
    float fg = block_sum(acc);
    float invfg = 1.0f / (fg + EPSV);

    __shared__ float gv[C_];
    for (int c = tid; c < C_; c += blockDim.x) {
        float t = 0.0f;
        for (int s = 0; s < S_; ++s) t += partial[s * C_ + c];
        gv[c] = t * invfg;
    }
    __syncthreads();

    float sq = 0.0f;
    for (int c = tid; c < C_; c += blockDim.x) sq += gv[c] * gv[c];
    float gn = block_sum(sq);
    gn = fmaxf(sqrtf(gn), 1e-12f);

    // T = sum msum; weights[m]=msum[m]/(T+EPS); wsum = sum weights
    float wa = (tid < M_) ? msum[tid] : 0.0f;
    float T = block_sum(wa);
    float wb = (tid < M_) ? msum[tid] / (T + EPSV) : 0.0f;
    float wsum = block_sum(wb);

    // proto norms: wave-parallel, no barriers (4 waves x 16 iterations)
    __shared__ float pn[M_];
    for (int m = wid; m < M_; m += 4) {
        float a = 0.0f;
        for (int c = lane; c < C_; c += 64) {
            float p = proto[m * C_ + c];
            a += p * p;
        }
        a = wave_sum(a);
        if (lane == 0) pn[m] = fmaxf(sqrtf(a), 1e-12f);
    }
    __syncthreads();

    // per-proto combined coefficient w_m / pn_m
    __shared__ float wq[M_];
    if (tid < M_) {
        float w = (msum[tid] / (T + EPSV)) / (wsum + EPSV);
        wq[tid] = w / pn[tid];
    }
    __syncthreads();

    for (int c = tid; c < C_; c += blockDim.x) {
        float vl = 0.0f;
        for (int m = 0; m < M_; ++m) vl += wq[m] * proto[m * C_ + c];
        v[c] = BETA_V * (gv[c] / gn) + (1.0f - BETA_V) * vl;
    }
}

// One block per 64 pixels; 4 waves split channels (96 each), LDS-combine.
__global__ __launch_bounds__(256) void k_score(const float* __restrict__ q,
                                               const float* __restrict__ v,
                                               float* __restrict__ out) {
    __shared__ float vs[C_];
    for (int c = threadIdx.x; c < C_; c += blockDim.x) vs[c] = v[c];
    __syncthreads();

    int wid = threadIdx.x >> 6;
    int lane = threadIdx.x & 63;
    int pixbase = blockIdx.x * 64;          // HW_ % 64 == 0 -> never spans b
    int b = pixbase / HW_;
    int p0 = pixbase - b * HW_;
    const float* qp = q + ((size_t)b * C_ + wid * 96) * HW_ + p0 + lane;

    float dot = 0.0f, sq = 0.0f;
#pragma unroll 8
    for (int c = 0; c < 96; ++c) {
        float val = qp[(size_t)c * HW_];
        dot += val * vs[wid * 96 + c];
        sq += val * val;
    }

    __shared__ float sdot[4][64];
    __shared__ float ssq[4][64];
    sdot[wid][lane] = dot;
    ssq[wid][lane] = sq;
    __syncthreads();
    if (wid == 0) {
        float d = sdot[0][lane] + sdot[1][lane] + sdot[2][lane] + sdot[3][lane];
        float s2 = ssq[0][lane] + ssq[1][lane] + ssq[2][lane] + ssq[3][lane];
        float sv = d / fmaxf(sqrtf(s2), 1e-12f);
        float o = sv / TEMP_V;
        float* ob = out + (size_t)b * 2 * HW_;
        ob[p0 + lane] = -o;
        ob[HW_ + p0 + lane] = o;
    }
}

extern "C" void kernel_launch(void* const* d_in, const int* in_sizes, int n_in,
                              void* d_out, int out_size, void* d_ws, size_t ws_size,
                              hipStream_t stream) {
    const float* support_feats = (const float*)d_in[0];
    const int* support_masks = (const int*)d_in[1];
    const float* query_feats = (const float*)d_in[2];
    const int* anchor_pos = (const int*)d_in[3];
    const int* anchor_sample = (const int*)d_in[4];
    const int* anchor_radius = (const int*)d_in[5];
    float* out = (float*)d_out;

    float* ws = (float*)d_ws;
    float* ws_partial = ws;                 // S*C = 1536
    float* ws_msum = ws_partial + S_ * C_;  // 64
    float* ws_proto = ws_msum + M_;         // M*C = 24576
    float* ws_v = ws_proto + M_ * C_;       // 384

    k_gpartial<<<S_ * C_, 256, 0, stream>>>(support_feats, support_masks, ws_partial);
    k_local<<<M_ * (C_ / 4), 256, 0, stream>>>(support_feats, support_masks, anchor_pos,
                                               anchor_sample, anchor_radius, ws_proto, ws_msum);
    k_finalize<<<1, 256, 0, stream>>>(support_masks, ws_partial, ws_msum, ws_proto, ws_v);
    k_score<<<B_ * HW_ / 64, 256, 0, stream>>>(query_feats, ws_v, out);
}

// Round 3
// 95.967 us; speedup vs baseline: 4.5606x; 1.0257x over previous
//
#include <hip/hip_runtime.h>
#include <hip/hip_bf16.h>
#include <math.h>

#define S_ 4
#define C_ 384
#define H_ 96
#define W_ 96
#define B_ 8
#define M_ 64
#define HW_ (H_ * W_)
#define EPSV 1e-6f
#define BETA_V 0.3f
#define TEMP_V 0.07f

#define NB_A (S_ * C_)        // 1536 gpartial blocks
#define NB_B (M_ * (C_ / 4))  // 6144 local blocks
#define NB_PREP (NB_A + NB_B + 1)

__device__ __forceinline__ float wave_sum(float v) {
#pragma unroll
    for (int o = 32; o; o >>= 1) v += __shfl_down(v, o, 64);
    return v;
}

__device__ __forceinline__ float block_sum(float v) {
    __shared__ float sm[8];
    int lane = threadIdx.x & 63;
    int wid = threadIdx.x >> 6;
    v = wave_sum(v);
    if (lane == 0) sm[wid] = v;
    __syncthreads();
    float r = 0.0f;
#pragma unroll
    for (int i = 0; i < 4; ++i) r += sm[i];
    __syncthreads();
    return r;
}

// Fused prep: role A = per-(s,c) masked plane sums; role B = per-(anchor,
// channel-group) window sums; role C = fg mask total.
__global__ __launch_bounds__(256) void k_prep(const float* __restrict__ feats,
                                              const int* __restrict__ mask,
                                              const int* __restrict__ pos,
                                              const int* __restrict__ samp,
                                              const int* __restrict__ rad,
                                              float* __restrict__ partial,
                                              float* __restrict__ proto,
                                              float* __restrict__ msum_out,
                                              float* __restrict__ fg_out) {
    int bid = blockIdx.x;
    int t = threadIdx.x;

    if (bid < NB_A) {
        // ---- role A: partial[sc] = sum_p feats[s,c,p] * mask[s,p]
        int s = bid / C_;
        const float4* fp = (const float4*)(feats + (size_t)bid * HW_);
        const int4* mp = (const int4*)(mask + (size_t)s * HW_);
        float acc = 0.0f;
        for (int i = t; i < HW_ / 4; i += 256) {
            float4 f = fp[i];
            int4 m = mp[i];
            acc += f.x * (float)m.x + f.y * (float)m.y + f.z * (float)m.z + f.w * (float)m.w;
        }
        float tot = block_sum(acc);
        if (t == 0) partial[bid] = tot;
        return;
    }
    bid -= NB_A;
    if (bid < NB_B) {
        // ---- role B: one block per (anchor m, channel-group of 4)
        const int CG = C_ / 4;  // 96
        int m = bid / CG;
        int cg = bid % CG;
        int y = pos[2 * m + 0];
        int x = pos[2 * m + 1];
        int s = samp[m];
        int ri = rad[m];
        int r = (ri == 0) ? 4 : (ri == 1) ? 8 : 16;
        int y0 = max(y - r, 0), y1 = min(y + r + 1, H_);
        int x0 = max(x - r, 0), x1 = min(x + r + 1, W_);
        int ww = x1 - x0;
        int n = (y1 - y0) * ww;

        __shared__ float mwin[33 * 33];
        const int* mp = mask + (size_t)s * HW_;
        float macc = 0.0f;
        {
            int yy = t / ww;          // one divide at setup
            int xx = t - yy * ww;
            int dy = 256 / ww, dx = 256 - dy * ww;  // dx < ww
            for (int i = t; i < n; i += 256) {
                float mv = (float)mp[(y0 + yy) * W_ + x0 + xx];
                mwin[i] = mv;
                macc += mv;
                xx += dx; yy += dy;
                if (xx >= ww) { xx -= ww; ++yy; }
            }
        }
        float msumv = block_sum(macc);  // internal barrier also publishes mwin
        if (cg == 0 && t == 0) msum_out[m] = msumv;
        float inv = 1.0f / (msumv + EPSV);

        int wid = t >> 6;
        int lane = t & 63;
        int c = cg * 4 + wid;
        const float* fp = feats + ((size_t)s * C_ + c) * HW_;
        float acc = 0.0f;
        {
            int yy = lane / ww;
            int xx = lane - yy * ww;
            int dy = 64 / ww, dx = 64 - dy * ww;
            for (int i = lane; i < n; i += 64) {
                acc += fp[(y0 + yy) * W_ + x0 + xx] * mwin[i];
                xx += dx; yy += dy;
                if (xx >= ww) { xx -= ww; ++yy; }
            }
        }
        acc = wave_sum(acc);
        if (lane == 0) proto[m * C_ + c] = acc * inv;
        return;
    }
    // ---- role C: fg = total mask sum
    const int4* mp4 = (const int4*)mask;
    float acc = 0.0f;
    for (int i = t; i < S_ * HW_ / 4; i += 256) {
        int4 m = mp4[i];
        acc += (float)(m.x + m.y + m.z + m.w);
    }
    float fg = block_sum(acc);
    if (t == 0) fg_out[0] = fg;
}

// Single block: combine into the final C-vector v. All inputs L2-resident.
__global__ __launch_bounds__(256) void k_finalize(const float* __restrict__ partial,
                                                  const float* __restrict__ msum,
                                                  const float* __restrict__ proto,
                                                  const float* __restrict__ fg_in,
                                                  float* __restrict__ v) {
    int tid = threadIdx.x;
    int wid = tid >> 6;
    int lane = tid & 63;

    float invfg = 1.0f / (fg_in[0] + EPSV);

    __shared__ float gv[C_];
    for (int c = tid; c < C_; c += 256) {
        float tv = 0.0f;
        for (int s = 0; s < S_; ++s) tv += partial[s * C_ + c];
        gv[c] = tv * invfg;
    }
    __syncthreads();

    float sq = 0.0f;
    for (int c = tid; c < C_; c += 256) sq += gv[c] * gv[c];
    float gn = block_sum(sq);
    gn = fmaxf(sqrtf(gn), 1e-12f);

    float wa = (tid < M_) ? msum[tid] : 0.0f;
    float T = block_sum(wa);
    float wb = (tid < M_) ? msum[tid] / (T + EPSV) : 0.0f;
    float wsum = block_sum(wb);

    // proto norms: wave-parallel
    __shared__ float pn[M_];
    for (int m = wid; m < M_; m += 4) {
        float a = 0.0f;
        for (int c = lane; c < C_; c += 64) {
            float p = proto[m * C_ + c];
            a += p * p;
        }
        a = wave_sum(a);
        if (lane == 0) pn[m] = fmaxf(sqrtf(a), 1e-12f);
    }
    __syncthreads();

    __shared__ float wq[M_];
    if (tid < M_) {
        float w = (msum[tid] / (T + EPSV)) / (wsum + EPSV);
        wq[tid] = w / pn[tid];
    }
    __syncthreads();

    for (int c = tid; c < C_; c += 256) {
        float vl = 0.0f;
        for (int m = 0; m < M_; ++m) vl += wq[m] * proto[m * C_ + c];
        v[c] = BETA_V * (gv[c] / gn) + (1.0f - BETA_V) * vl;
    }
}

// One block per 256 pixels; 4 waves split channels (96 each); float4 loads
// (4 pixels per thread, 16 B/lane); LDS combine; float4 stores.
__global__ __launch_bounds__(256) void k_score(const float* __restrict__ q,
                                               const float* __restrict__ v,
                                               float* __restrict__ out) {
    __shared__ float vs[C_];
    for (int c = threadIdx.x; c < C_; c += 256) vs[c] = v[c];
    __syncthreads();

    int wid = threadIdx.x >> 6;
    int lane = threadIdx.x & 63;
    int pixbase = blockIdx.x * 256;  // HW_ % 256 == 0 -> never spans b
    int b = pixbase / HW_;
    int p0 = pixbase - b * HW_;
    const float4* qp = (const float4*)(q + ((size_t)b * C_ + wid * 96) * HW_ + p0);

    float4 dot = {0.f, 0.f, 0.f, 0.f};
    float4 sq = {0.f, 0.f, 0.f, 0.f};
#pragma unroll 8
    for (int c = 0; c < 96; ++c) {
        float4 f = qp[(size_t)c * (HW_ / 4) + lane];
        float vc = vs[wid * 96 + c];
        dot.x += f.x * vc; dot.y += f.y * vc; dot.z += f.z * vc; dot.w += f.w * vc;
        sq.x += f.x * f.x; sq.y += f.y * f.y; sq.z += f.z * f.z; sq.w += f.w * f.w;
    }

    __shared__ float4 sd[4][64];
    __shared__ float4 ss[4][64];
    sd[wid][lane] = dot;
    ss[wid][lane] = sq;
    __syncthreads();
    if (wid == 0) {
        float4 d = sd[0][lane];
        float4 s2 = ss[0][lane];
#pragma unroll
        for (int w = 1; w < 4; ++w) {
            float4 a = sd[w][lane];
            float4 b2 = ss[w][lane];
            d.x += a.x; d.y += a.y; d.z += a.z; d.w += a.w;
            s2.x += b2.x; s2.y += b2.y; s2.z += b2.z; s2.w += b2.w;
        }
        float4 o;
        o.x = (d.x / fmaxf(sqrtf(s2.x), 1e-12f)) / TEMP_V;
        o.y = (d.y / fmaxf(sqrtf(s2.y), 1e-12f)) / TEMP_V;
        o.z = (d.z / fmaxf(sqrtf(s2.z), 1e-12f)) / TEMP_V;
        o.w = (d.w / fmaxf(sqrtf(s2.w), 1e-12f)) / TEMP_V;
        float4 no = {-o.x, -o.y, -o.z, -o.w};
        float* ob = out + (size_t)b * 2 * HW_;
        ((float4*)(ob + p0))[lane] = no;
        ((float4*)(ob + HW_ + p0))[lane] = o;
    }
}

extern "C" void kernel_launch(void* const* d_in, const int* in_sizes, int n_in,
                              void* d_out, int out_size, void* d_ws, size_t ws_size,
                              hipStream_t stream) {
    const float* support_feats = (const float*)d_in[0];
    const int* support_masks = (const int*)d_in[1];
    const float* query_feats = (const float*)d_in[2];
    const int* anchor_pos = (const int*)d_in[3];
    const int* anchor_sample = (const int*)d_in[4];
    const int* anchor_radius = (const int*)d_in[5];
    float* out = (float*)d_out;

    float* ws = (float*)d_ws;
    float* ws_partial = ws;                 // S*C = 1536
    float* ws_msum = ws_partial + S_ * C_;  // 64
    float* ws_proto = ws_msum + M_;         // M*C = 24576
    float* ws_v = ws_proto + M_ * C_;       // 384
    float* ws_fg = ws_v + C_;               // 1

    k_prep<<<NB_PREP, 256, 0, stream>>>(support_feats, support_masks, anchor_pos,
                                        anchor_sample, anchor_radius,
                                        ws_partial, ws_proto, ws_msum, ws_fg);
    k_finalize<<<1, 256, 0, stream>>>(ws_partial, ws_msum, ws_proto, ws_fg, ws_v);
    k_score<<<B_ * HW_ / 256, 256, 0, stream>>>(query_feats, ws_v, out);
}